// Round 12
// baseline (103.080 us; speedup 1.0000x reference)
//
#include <hip/hip_runtime.h>
#include <math.h>

#define K1_NR 8    // k1 rows per block strip
#define SROWS 64   // pool rows per block strip
#define PCH   16   // pool rows per LDS phase
#define QCAP  1024 // k4 compaction queue entries

// ---------------- device helpers ----------------

__device__ __forceinline__ float srgb_to_linear(float x) {
    x = fminf(fmaxf(x, 0.0f), 1.0f);
    return (x <= 0.04045f) ? x * (1.0f / 12.92f)
                           : powf((x + 0.055f) * (1.0f / 1.055f), 2.4f);
}

__device__ __forceinline__ void oklab_ab(float r, float g, float b,
                                         float& A, float& Bc) {
    r = srgb_to_linear(r);
    g = srgb_to_linear(g);
    b = srgb_to_linear(b);
    float l = 0.4122214708f * r + 0.5363325363f * g + 0.0514459929f * b;
    float m = 0.2119034982f * r + 0.6806995451f * g + 0.1073969566f * b;
    float s = 0.0883024619f * r + 0.2817188376f * g + 0.6299787005f * b;
    l = cbrtf(fmaxf(l, 1e-10f));
    m = cbrtf(fmaxf(m, 1e-10f));
    s = cbrtf(fmaxf(s, 1e-10f));
    A  = 1.9779984951f * l - 2.428592205f * m + 0.4505937099f * s;
    Bc = 0.0259040371f * l + 0.7827717662f * m - 0.808675766f  * s;
}

__device__ __forceinline__ void color_terms(const float* __restrict__ pred,
                                            const float* __restrict__ target,
                                            size_t off, size_t HWp, float m,
                                            float& sc, float& sh) {
    float pa, pb, ta, tb;
    oklab_ab(pred[off], pred[off + HWp], pred[off + 2 * HWp], pa, pb);
    oklab_ab(target[off], target[off + HWp], target[off + 2 * HWp], ta, tb);
    float Cp = sqrtf(pa * pa + pb * pb + 1e-12f);
    float Cg = sqrtf(ta * ta + tb * tb + 1e-12f);
    sc += fabsf(Cp - Cg) * m;
    float cosd = (pa * ta + pb * tb) / (Cp * Cg + 1e-12f);
    cosd = fminf(fmaxf(cosd, -1.0f), 1.0f);
    sh += fmaxf(Cg, 0.01f) * (1.0f - cosd) * m;
}

// ---------------- K1: sobel edge_soft, ONE CHANNEL PER WAVE -----------------
// Every prior variant had each wave pulling 3 channel streams from HBM and
// pinned at ~1.6-2.2 TB/s. Here wave w reads ONLY channel w (single stream
// per wave, like the 6.3 TB/s copy reference). 10 independent float4 row
// loads fully unrolled (deep MLP); halo cols are L1 hits (covered by the
// neighbor lane's float4 line). Channel max via 24 KB LDS + one barrier.

__device__ __forceinline__ float4 k1_sobel_g(const float4& pr, const float4& cu,
                                             const float4& nx,
                                             float lpr, float lcu, float lnx,
                                             float rpr, float rcu, float rnx) {
    float4 u, v;
    u.x = fmaf(2.f, cu.x, pr.x) + nx.x;
    u.y = fmaf(2.f, cu.y, pr.y) + nx.y;
    u.z = fmaf(2.f, cu.z, pr.z) + nx.z;
    u.w = fmaf(2.f, cu.w, pr.w) + nx.w;
    v.x = nx.x - pr.x; v.y = nx.y - pr.y;
    v.z = nx.z - pr.z; v.w = nx.w - pr.w;
    float ul = fmaf(2.f, lcu, lpr) + lnx;
    float vl = lnx - lpr;
    float ur = fmaf(2.f, rcu, rpr) + rnx;
    float vr = rnx - rpr;
    float4 g;
    g.x = fabsf(u.y - ul)  + fabsf(fmaf(2.f, v.x, vl) + v.y);
    g.y = fabsf(u.z - u.x) + fabsf(fmaf(2.f, v.y, v.x) + v.z);
    g.z = fabsf(u.w - u.y) + fabsf(fmaf(2.f, v.z, v.y) + v.w);
    g.w = fabsf(ur - u.z)  + fabsf(fmaf(2.f, v.w, v.z) + vr);
    return g;
}

__global__ __launch_bounds__(192) void k1_edge(const float* __restrict__ target,
                                               float* __restrict__ edge,
                                               int H, int W) {
    __shared__ float4 s_g[3][K1_NR][64];   // 24 KB

    int strips = H / K1_NR;                // 128
    int cgs = W >> 8;                      // 4 col-groups of 256
    int blk = blockIdx.x;
    int b   = blk / (strips * cgs);
    int rem = blk % (strips * cgs);
    int strip = rem / cgs, cg = rem % cgs;
    int f0 = strip * K1_NR;
    int lane = threadIdx.x & 63;
    int wv   = threadIdx.x >> 6;           // 0..2 == channel
    int col0 = (cg << 8) + (lane << 2);
    size_t HW = (size_t)H * W;
    const float* p = target + (size_t)b * 3 * HW + (size_t)wv * HW;

    bool lok = (col0 > 0);
    bool rok = (col0 + 4 < W);
    int lc = lok ? col0 - 1 : 0;
    int rc = rok ? col0 + 4 : 0;

    // 10 independent row loads (rows f0-1 .. f0+8), zero-padded vertically
    float4 w[K1_NR + 2];
    float wl[K1_NR + 2], wr[K1_NR + 2];
#pragma unroll
    for (int i = 0; i < K1_NR + 2; ++i) {
        int r = f0 - 1 + i;
        bool oky = (r >= 0) && (r < H);
        const float* rp = p + (size_t)r * W;
        w[i]  = oky ? *(const float4*)(rp + col0)
                    : make_float4(0.f, 0.f, 0.f, 0.f);
        wl[i] = (oky && lok) ? rp[lc] : 0.f;
        wr[i] = (oky && rok) ? rp[rc] : 0.f;
    }
#pragma unroll
    for (int k = 0; k < K1_NR; ++k) {
        s_g[wv][k][lane] = k1_sobel_g(w[k], w[k + 1], w[k + 2],
                                      wl[k], wl[k + 1], wl[k + 2],
                                      wr[k], wr[k + 1], wr[k + 2]);
    }
    __syncthreads();

    float* ep = edge + (size_t)b * HW + (size_t)(cg << 8);
    for (int i = threadIdx.x; i < K1_NR * 64; i += 192) {
        int row = i >> 6, l = i & 63;
        float4 g0 = s_g[0][row][l];
        float4 g1 = s_g[1][row][l];
        float4 g2 = s_g[2][row][l];
        float4 e;
        e.x = fminf(2.f * fmaxf(g0.x, fmaxf(g1.x, g2.x)), 1.f);
        e.y = fminf(2.f * fmaxf(g0.y, fmaxf(g1.y, g2.y)), 1.f);
        e.z = fminf(2.f * fmaxf(g0.z, fmaxf(g1.z, g2.z)), 1.f);
        e.w = fminf(2.f * fmaxf(g0.w, fmaxf(g1.w, g2.w)), 1.f);
        *(float4*)(ep + (size_t)(f0 + row) * W + (l << 2)) = e;
    }
}

// ---------------- column-strip 2-D pool (vertical in regs, horizontal via LDS) ----

template <int R, bool ISMAX, bool SUB_EDGE>
__global__ __launch_bounds__(256) void pool_kernel(const float* __restrict__ in,
                                                   const float* __restrict__ edge,
                                                   float* __restrict__ out,
                                                   int H, int W) {
    const int OUTW = 256 - 2 * R;
    __shared__ float s_v[PCH][256];
    int cb = (W + OUTW - 1) / OUTW;
    int rs = H / SROWS;
    int blk = blockIdx.x;
    int b   = blk / (cb * rs);
    int t   = blk % (cb * rs);
    int bxi = t / rs, ysi = t % rs;
    int tid = threadIdx.x;
    int col = bxi * OUTW - R + tid;
    int cc  = min(max(col, 0), W - 1);  // replicate == clamped window
    size_t base = (size_t)b * H * W;
    const float* colp = in + base + cc;
    int ys = ysi * SROWS;
    bool writer = (tid >= R) && (tid < OUTW + R) && (col < W);

    for (int ph = 0; ph < SROWS / PCH; ++ph) {
        int y0 = ys + ph * PCH;
        float w[PCH + 2 * R];
#pragma unroll
        for (int k = 0; k < PCH + 2 * R; ++k) {
            int r = min(max(y0 - R + k, 0), H - 1);
            w[k] = colp[(size_t)r * W];
        }
        float v[PCH];
#pragma unroll
        for (int k = 0; k < PCH; ++k) {
            float m = w[k];
#pragma unroll
            for (int d = 1; d <= 2 * R; ++d)
                m = ISMAX ? fmaxf(m, w[k + d]) : fminf(m, w[k + d]);
            v[k] = m;
        }
        __syncthreads();  // previous phase's readers done
#pragma unroll
        for (int k = 0; k < PCH; ++k) s_v[k][tid] = v[k];
        __syncthreads();
        if (writer) {
#pragma unroll
            for (int k = 0; k < PCH; ++k) {
                float m = s_v[k][tid - R];
#pragma unroll
                for (int d = 1; d <= 2 * R; ++d)
                    m = ISMAX ? fmaxf(m, s_v[k][tid - R + d])
                              : fminf(m, s_v[k][tid - R + d]);
                size_t gi = base + (size_t)(y0 + k) * W + col;
                out[gi] = SUB_EDGE ? fmaxf(m - edge[gi], 0.f) : m;
            }
        }
    }
}

// ---------------- K4: 5x5 max-pool + compacted masked OKLab loss ----------------

__global__ __launch_bounds__(256) void k4_loss(const float* __restrict__ pred,
                                               const float* __restrict__ target,
                                               const float* __restrict__ mask0,
                                               float* __restrict__ partials,
                                               int H, int W, int nb) {
    const int R = 2, OUTW = 256 - 2 * R;
    __shared__ float s_v[PCH][256];
    __shared__ int   q_pos[QCAP];
    __shared__ float q_m[QCAP];
    __shared__ int   cnt;
    __shared__ float s_red[3][4];

    int cb = (W + OUTW - 1) / OUTW;
    int rs = H / SROWS;
    int blk = blockIdx.x;
    int b   = blk / (cb * rs);
    int t   = blk % (cb * rs);
    int bxi = t / rs, ysi = t % rs;
    int tid = threadIdx.x;
    int col = bxi * OUTW - R + tid;
    int cc  = min(max(col, 0), W - 1);
    size_t HWp  = (size_t)H * W;
    size_t base = (size_t)b * HWp;
    size_t cbase = (size_t)b * 3 * HWp;
    const float* colp = mask0 + base + cc;
    int ys = ysi * SROWS;
    bool writer = (tid >= R) && (tid < OUTW + R) && (col < W);

    float sm = 0.f, sc = 0.f, sh = 0.f;

    for (int ph = 0; ph < SROWS / PCH; ++ph) {
        int y0 = ys + ph * PCH;
        float w[PCH + 2 * R];
#pragma unroll
        for (int k = 0; k < PCH + 2 * R; ++k) {
            int r = min(max(y0 - R + k, 0), H - 1);
            w[k] = colp[(size_t)r * W];
        }
        float v[PCH];
#pragma unroll
        for (int k = 0; k < PCH; ++k) {
            float m = w[k];
#pragma unroll
            for (int d = 1; d <= 2 * R; ++d) m = fmaxf(m, w[k + d]);
            v[k] = m;
        }
        __syncthreads();  // prev phase queue-processing done
#pragma unroll
        for (int k = 0; k < PCH; ++k) s_v[k][tid] = v[k];
        if (tid == 0) cnt = 0;
        __syncthreads();
        if (writer) {
#pragma unroll
            for (int k = 0; k < PCH; ++k) {
                float m = s_v[k][tid - R];
#pragma unroll
                for (int d = 1; d <= 2 * R; ++d)
                    m = fmaxf(m, s_v[k][tid - R + d]);
                sm += m;
                if (m > 0.f) {
                    int pos = atomicAdd(&cnt, 1);
                    if (pos < QCAP) {
                        q_pos[pos] = ((y0 + k) << 16) | col;
                        q_m[pos] = m;
                    } else {  // overflow fallback (dense mask) — compute inline
                        color_terms(pred, target,
                                    cbase + (size_t)(y0 + k) * W + col,
                                    HWp, m, sc, sh);
                    }
                }
            }
        }
        __syncthreads();
        int n = min(cnt, QCAP);
        for (int i = tid; i < n; i += 256) {
            int pk = q_pos[i];
            color_terms(pred, target,
                        cbase + (size_t)(pk >> 16) * W + (pk & 0xffff),
                        HWp, q_m[i], sc, sh);
        }
    }

    // wave reduce (64 lanes)
#pragma unroll
    for (int off = 32; off > 0; off >>= 1) {
        sm += __shfl_down(sm, off);
        sc += __shfl_down(sc, off);
        sh += __shfl_down(sh, off);
    }
    int lane = tid & 63, wav = tid >> 6;
    __syncthreads();
    if (lane == 0) { s_red[0][wav] = sm; s_red[1][wav] = sc; s_red[2][wav] = sh; }
    __syncthreads();
    if (tid == 0) {
        float tm = 0, tc = 0, th = 0;
        for (int i = 0; i < 4; ++i) {
            tm += s_red[0][i]; tc += s_red[1][i]; th += s_red[2][i];
        }
        partials[blk]          = tm;
        partials[nb + blk]     = tc;
        partials[2 * nb + blk] = th;
    }
}

__global__ void finalize_kernel(const float* __restrict__ partials, int nb,
                                float* __restrict__ out) {
    double sm = 0.0, sc = 0.0, sh = 0.0;
    for (int i = threadIdx.x; i < nb; i += blockDim.x) {
        sm += (double)partials[i];
        sc += (double)partials[nb + i];
        sh += (double)partials[2 * nb + i];
    }
    __shared__ double red[3][256];
    red[0][threadIdx.x] = sm;
    red[1][threadIdx.x] = sc;
    red[2][threadIdx.x] = sh;
    __syncthreads();
    for (int s = blockDim.x / 2; s > 0; s >>= 1) {
        if ((int)threadIdx.x < s) {
            red[0][threadIdx.x] += red[0][threadIdx.x + s];
            red[1][threadIdx.x] += red[1][threadIdx.x + s];
            red[2][threadIdx.x] += red[2][threadIdx.x + s];
        }
        __syncthreads();
    }
    if (threadIdx.x == 0) {
        double ms = fmax(red[0][0], 1.0);
        out[0] = (float)(red[1][0] / ms + 2.0 * red[2][0] / ms);
    }
}

// ---------------- host launch ----------------

extern "C" void kernel_launch(void* const* d_in, const int* in_sizes, int n_in,
                              void* d_out, int out_size, void* d_ws, size_t ws_size,
                              hipStream_t stream) {
    const float* pred   = (const float*)d_in[0];
    const float* target = (const float*)d_in[1];
    float* out = (float*)d_out;

    const int H = 1024, W = 1024;  // fixed problem shape (W%256==0 required by k1)
    int Bn = in_sizes[0] / (3 * H * W);
    size_t plane = (size_t)Bn * H * W * sizeof(float);

    char* ws = (char*)d_ws;
    float* planeA = (float*)ws;            // edge, then mask0 (in place)
    float* planeB = (float*)(ws + plane);  // dilated
    float* partials = (float*)(ws + 2 * plane);

    int g1 = Bn * (H / K1_NR) * (W >> 8);      // 4096
    int rs = H / SROWS;                        // 16
    int cbP = (W + 245) / 246;                 // 5
    int cb4 = (W + 251) / 252;                 // 5
    int gP = Bn * cbP * rs;
    int g4 = Bn * cb4 * rs;

    // 1. sobel edge_soft -> planeA (one channel per wave)
    k1_edge<<<g1, 192, 0, stream>>>(target, planeA, H, W);
    // 2. 11x11 max-pool -> planeB (dilated)
    pool_kernel<5, true, false><<<gP, 256, 0, stream>>>(planeA, nullptr, planeB, H, W);
    // 3. 11x11 min-pool + relu(closed - edge) -> planeA in place (mask0)
    pool_kernel<5, false, true><<<gP, 256, 0, stream>>>(planeB, planeA, planeA, H, W);
    // 4. 5x5 max-pool + compacted masked loss -> partials
    k4_loss<<<g4, 256, 0, stream>>>(pred, target, planeA, partials, H, W, g4);
    // 5. final reduce + combine
    finalize_kernel<<<1, 256, 0, stream>>>(partials, g4, out);
}